// Round 3
// baseline (31.302 us; speedup 1.0000x reference)
//
#include <hip/hip_runtime.h>

// MeanPooling: xs [B=16, T=2048, D=1024] fp32, xs_len [B] (int64 or int32), out [B, D] fp32.
// out[b][d] = sum_{t < len_b} xs[b][t][d] / len_b
//
// Two-phase, no atomics, no memset, PROPORTIONAL load balancing:
//   Both kernels recompute (deterministically) from xs_len:
//     total   = sum(len_b)
//     cnt_b   = ceil(len_b * NB / total)   (blocks assigned to sample b)
//     pref_b  = prefix sum of cnt_b
//   K1: block i -> sample b with pref_b <= i < pref_{b+1}, slot j = i - pref_b,
//       sums rows [j*len_b/cnt_b, (j+1)*len_b/cnt_b) into ws[i][0:1024].
//       Every block handles ~total/NB rows -> near-perfect CU balance.
//   K2: block (b, c) reduces slots [pref_b, pref_b + cnt_b) for D-chunk c,
//       scales by 1/len_b, writes out.

#define B_ 16
#define T_ 2048
#define D_ 1024
#define NB 1024          // target active blocks in K1

__device__ __forceinline__ void read_lens(const void* len_ptr, int* lens)
{
    // Sniff xs_len dtype: if stored as int64, element 0 read as i64 is in [1, T_].
    // If stored as int32, the first i64 read = len0 | (len1 << 32) >= 2^32 (len1 >= 1).
    const long long v0 = ((const long long*)len_ptr)[0];
    const bool is64 = (v0 >= 1 && v0 <= (long long)T_);
    #pragma unroll
    for (int b = 0; b < B_; ++b) {
        long long len = is64 ? ((const long long*)len_ptr)[b]
                             : (long long)((const int*)len_ptr)[b];
        if (len < 1) len = 1;
        if (len > T_) len = T_;
        lens[b] = (int)len;
    }
}

// cnt[b], pref[0..B_] from lens. pref[B_] <= NB + B_.
__device__ __forceinline__ void partition(const int* lens, int* cnt, int* pref)
{
    int total = 0;
    #pragma unroll
    for (int b = 0; b < B_; ++b) total += lens[b];
    int p = 0;
    #pragma unroll
    for (int b = 0; b < B_; ++b) {
        pref[b] = p;
        cnt[b] = (lens[b] * NB + total - 1) / total;   // >= 1
        p += cnt[b];
    }
    pref[B_] = p;
}

__global__ __launch_bounds__(256) void mp_partial(
    const float* __restrict__ xs,
    const void* __restrict__ len_ptr,
    float* __restrict__ ws)
{
    int lens[B_], cnt[B_], pref[B_ + 1];
    read_lens(len_ptr, lens);
    partition(lens, cnt, pref);

    const int bid = blockIdx.x;
    if (bid >= pref[B_]) return;

    // find sample b: pref[b] <= bid < pref[b+1]
    int b = 0;
    #pragma unroll
    for (int k = 0; k < B_; ++k) {
        if (bid >= pref[k + 1]) b = k + 1;
    }
    const int j = bid - pref[b];
    const int len = lens[b];
    const int cb = cnt[b];
    const int r0 = (int)((long)j * len / cb);
    const int r1 = (int)((long)(j + 1) * len / cb);

    const int tid = threadIdx.x;     // 256 threads x float4 = 1024 floats = full D row

    const float4* src = (const float4*)xs + ((long)b * T_ + r0) * (D_ / 4) + tid;
    float4 acc = make_float4(0.f, 0.f, 0.f, 0.f);

    #pragma unroll 4
    for (int t = r0; t < r1; ++t) {
        float4 v = *src;
        src += (D_ / 4);
        acc.x += v.x; acc.y += v.y; acc.z += v.z; acc.w += v.w;
    }

    ((float4*)ws)[(long)bid * (D_ / 4) + tid] = acc;
}

__global__ __launch_bounds__(256) void mp_reduce(
    const float* __restrict__ ws,
    const void* __restrict__ len_ptr,
    float* __restrict__ out)
{
    int lens[B_], cnt[B_], pref[B_ + 1];
    read_lens(len_ptr, lens);
    partition(lens, cnt, pref);

    const int b = blockIdx.x >> 2;   // 4 blocks per sample
    const int c = blockIdx.x & 3;    // D-chunk: 256 floats = 64 float4
    const int lane = threadIdx.x & 63;
    const int w = threadIdx.x >> 6;  // 4 waves stride the slots

    const int s0 = pref[b];
    const int s1 = pref[b + 1];

    const int d4 = c * 64 + lane;    // float4 index in [0, 256)
    const float4* wsp = (const float4*)ws;

    float4 acc = make_float4(0.f, 0.f, 0.f, 0.f);
    for (int s = s0 + w; s < s1; s += 4) {
        float4 v = wsp[(long)s * (D_ / 4) + d4];
        acc.x += v.x; acc.y += v.y; acc.z += v.z; acc.w += v.w;
    }

    __shared__ float4 sm[4][64];
    sm[w][lane] = acc;
    __syncthreads();

    if (w == 0) {
        float4 a0 = sm[0][lane], a1 = sm[1][lane], a2 = sm[2][lane], a3 = sm[3][lane];
        const float inv = 1.0f / (float)lens[b];
        float4 r;
        r.x = (a0.x + a1.x + a2.x + a3.x) * inv;
        r.y = (a0.y + a1.y + a2.y + a3.y) * inv;
        r.z = (a0.z + a1.z + a2.z + a3.z) * inv;
        r.w = (a0.w + a1.w + a2.w + a3.w) * inv;
        ((float4*)out)[(long)b * (D_ / 4) + d4] = r;
    }
}

extern "C" void kernel_launch(void* const* d_in, const int* in_sizes, int n_in,
                              void* d_out, int out_size, void* d_ws, size_t ws_size,
                              hipStream_t stream)
{
    const float* xs = (const float*)d_in[0];
    const void* xs_len = d_in[1];
    float* out = (float*)d_out;
    float* ws = (float*)d_ws;    // uses up to (NB + B_) * D_ * 4 B ~= 4.06 MiB

    mp_partial<<<dim3(NB + B_), dim3(256), 0, stream>>>(xs, xs_len, ws);
    mp_reduce<<<dim3(B_ * 4), dim3(256), 0, stream>>>(ws, xs_len, out);
}